// Round 10
// baseline (109.807 us; speedup 1.0000x reference)
//
#include <hip/hip_runtime.h>
#include <math.h>

// R15: 2 LANES/RAY FOR PH1+PH3, DENSE 64-LANE PH2 ON WAVE 0. NT=128, 64
// rays/block, 2048 blocks -> ph1/ph3 run at 4 waves/SIMD (halved serial
// length, doubled TLP); ph2 (unsplittable serial machine) runs once per ray
// on wave 0 only -- chip-wide ph2 issue IDENTICAL to R6/R14b (R5's fatal
// flaw was duplicating ph2 issue across 2x waves). Wave 1 parks at the
// barrier during ph2 (parked waves issue nothing). Ray state (e00,kV0,Sinv)
// crosses lanes via a 768B LDS stage. R5's verified-exact split math (T-
// factorized fixups, merge-path diagonal with the walk's own comparator) +
// R6/R14b off-chain algebra (mult-form chains, speculative opn, depth-2 ds
// prefetch, u-increment). LDS 17.4KB -> 8 blocks/CU = 16 waves/CU.
// launch_bounds(128,4) caps VGPR at 128.

#define NT 128
#define PTS 64
#define NRAYS (2*256*256)
#define NEARV 0.1f
#define STEPV (1.9f/63.0f)
#define FAR63 (0.1f + 63.0f*(1.9f/63.0f))
#define NL2E (-1.4426950408889634f)
#define ECLAMP 1.0e37f

__global__ __launch_bounds__(NT, 4) void nerf_main(
    const float* __restrict__ tm, const float* __restrict__ wq,
    float* __restrict__ out, unsigned int* __restrict__ bmm)
{
    __shared__ float fd[PTS + 1][64];      // [depth-slot][ray-local] + pad row
    __shared__ float sE00[64], sKV0[64], sSinv[64];
    __shared__ unsigned smn2[2], smx2[2];
    const int tid = threadIdx.x;
    const int rl  = tid >> 1;              // ray-local 0..63
    const int h   = tid & 1;               // half: 0 = pts 0..31, 1 = 32..63
    const int r   = blockIdx.x * 64 + rl;  // global ray
    const int b = r >> 16, n = r & 65535;
    const int i = n >> 8, j = n & 255;

    float bA[4], sA[4];                    // feat[c]*(-log2e) = bA + d*sA
    {
        float cx = (1.0f + (float)j * (-2.0f/255.0f)) * (1.0f/4.2f);
        float cy = (1.0f + (float)i * (-2.0f/255.0f)) * (1.0f/4.2f);
        const float* tmb = tm + b*12;
        float dx = tmb[0]*cx + tmb[1]*cy + tmb[2];
        float dy = tmb[4]*cx + tmb[5]*cy + tmb[6];
        float dz = tmb[8]*cx + tmb[9]*cy + tmb[10];
        float ox = tmb[3], oy = tmb[7], oz = tmb[11];
        #pragma unroll
        for (int c = 0; c < 4; c++) {
            float s  = dx*wq[0*4+c] + dy*wq[1*4+c] + dz*wq[2*4+c];
            float bv = ox*wq[0*4+c] + oy*wq[1*4+c] + oz*wq[2*4+c]
                     + dx*wq[3*4+c] + dy*wq[4*4+c] + dz*wq[5*4+c];
            sA[c] = s * NL2E;
            bA[c] = bv * NL2E;
        }
    }

    // recurrence consts; each lane starts its half at its own depth
    float kV[4], eV[4];
    float e00 = __builtin_amdgcn_exp2f(bA[0] + NEARV*sA[0]);
    float dstart = h ? fmaf(32.0f, STEPV, NEARV) : NEARV;
    #pragma unroll
    for (int c = 0; c < 4; c++) {
        kV[c] = __builtin_amdgcn_exp2f(sA[c]*STEPV);
        eV[c] = __builtin_amdgcn_exp2f(bA[c] + dstart*sA[c]);
    }

    // ---- phase 1: coarse march, 32 pts/lane, mult-form chain ----
    float T = 1.0f, Sw = 0.0f;
    float a0 = 0.0f, a1 = 0.0f, a2 = 0.0f;
    #pragma unroll 4
    for (int p = 0; p < 32; p++) {
        float e0c = fminf(eV[0], ECLAMP);
        float r0 = __builtin_amdgcn_rcpf(1.0f + e0c);  // op
        float m0 = e0c * r0;                           // 1-op, off-chain
        float v0 = __builtin_amdgcn_rcpf(1.0f + eV[1]);
        float v1 = __builtin_amdgcn_rcpf(1.0f + eV[2]);
        float v2 = __builtin_amdgcn_rcpf(1.0f + eV[3]);
        eV[0] *= kV[0];
        eV[1] *= kV[1];
        eV[2] *= kV[2];
        eV[3] *= kV[3];
        float w = r0 * T;
        a0 = fmaf(w, v0, a0);
        a1 = fmaf(w, v1, a1);
        a2 = fmaf(w, v2, a2);
        Sw += w;
        T *= m0;                                       // chain: one v_mul
    }
    // pair fixup: full = A_half + T_midA * B_half (accumulators linear in T)
    float oT = __shfl_xor(T, 1, 64);
    float oS = __shfl_xor(Sw, 1, 64);
    float o0 = __shfl_xor(a0, 1, 64);
    float o1 = __shfl_xor(a1, 1, 64);
    float o2 = __shfl_xor(a2, 1, 64);
    float T_mid = h ? oT : T;
    float Sfull = (h ? oS : Sw) + T_mid * (h ? Sw : oS) + 64.0f*1e-5f;
    float A0 = (h ? o0 : a0) + T_mid * (h ? a0 : o0);
    float A1 = (h ? o1 : a1) + T_mid * (h ? a1 : o1);
    float A2 = (h ? o2 : a2) + T_mid * (h ? a2 : o2);
    if (h == 0) {
        out[(b*3+0)*65536 + n] = A0;
        out[(b*3+1)*65536 + n] = A1;
        out[(b*3+2)*65536 + n] = A2;
        sE00[rl]  = e00;                   // stage ray state for dense ph2
        sKV0[rl]  = kV[0];
        sSinv[rl] = __builtin_amdgcn_rcpf(Sfull);
    }
    __syncthreads();

    // ---- phase 2: dense sampling machines on wave 0 (1 machine / ray) ----
    if (tid < 64) {
        const int q = tid;
        float e0q = sE00[q];
        float kq  = sKV0[q];
        float Siq = sSinv[q];
        float op0 = __builtin_amdgcn_rcpf(1.0f + e0q); // sigmoid at d = NEAR
        float T2   = 1.0f - op0;
        float c_lo = 0.0f;
        float c_hi = (op0 + 1e-5f) * Siq;              // cdf[0]
        int ind = 0, wslot = 0;
        float u = 0.015625f;                           // k/64, exact increments
        float bin_prev = NEARV;                        // bin_0 == NEAR always
        float eP  = e0q * kq;                          // index m = 1
        float opn = __builtin_amdgcn_rcpf(1.0f + eP);
        #pragma unroll 2
        for (int it = 0; it < 2*PTS; it++) {
            float eP2  = eP * kq;                      // speculative advance
            float opnB = __builtin_amdgcn_rcpf(1.0f + eP2); // off-chain rcp
            bool adv = (ind < PTS) && (c_hi <= u);     // searchsorted 'right'
            float wn  = opn * T2;
            float d0  = fmaf((float)(ind - 1), STEPV, NEARV);
            float den = c_hi - c_lo;
            den = (den < 1e-8f) ? 1.0f : den;          // ref guard
            float t = (u - c_lo) * __builtin_amdgcn_rcpf(den);
            t = fminf(fmaxf(t, 0.0f), 1.0f);
            float bin = fmaf(t, STEPV, d0);
            bin = (ind <= 0)   ? NEARV : bin;
            bin = (ind >= PTS) ? FAR63 : bin;
            float fdep = 0.5f * (bin_prev + bin);
            int widx = adv ? PTS : wslot;              // pad row on advance
            fd[widx][q] = fdep;                        // unconditional ds_write
            float nc_hi = c_hi + (wn + 1e-5f) * Siq;
            float nT2   = T2 * (1.0f - opn);
            bool advm   = adv && (ind < 62);           // m=min(ind+1,63) moves
            c_lo     = adv ? c_hi : c_lo;
            c_hi     = adv ? nc_hi : c_hi;
            T2       = adv ? nT2 : T2;
            bin_prev = adv ? bin_prev : bin;
            eP  = advm ? eP2  : eP;
            opn = advm ? opnB : opn;                   // select, not recompute
            ind += adv ? 1 : 0;
            u  += adv ? 0.0f : 0.015625f;              // exact k/64 increments
            wslot = adv ? wslot : min(wslot + 1, PTS);
        }
    }
    __syncthreads();

    // ---- phase 3: split merge, 64 steps/lane, merge-path start for odd ----
    int pc, pf;
    if (h) {                               // largest ii with P(ii):
        int lo = 0, hi = 64;               // P = (ii==0)||coarse(ii-1)<=fine(64-ii)
        #pragma unroll
        for (int s = 0; s < 7; s++) {
            int mid = (lo + hi + 1) >> 1;
            float cd = fmaf((float)(mid - 1), STEPV, NEARV);
            float fv = fd[64 - mid][rl];   // mid==0 -> pad row, overridden
            bool p = (mid == 0) || (cd <= fv);
            lo = p ? mid : lo;
            hi = p ? hi : mid - 1;
        }
        pc = lo; pf = 64 - lo;
    } else {
        pc = 0; pf = 0;
    }
    const float bA0 = bA[0], sA0 = sA[0], bA1 = bA[1], sA1 = sA[1];
    const float bA2 = bA[2], sA2 = sA[2], bA3 = bA[3], sA3 = sA[3];
    float dc  = fmaf((float)pc, STEPV, NEARV);
    float cur = fd[min(pf, PTS)][rl];
    float nxt = fd[min(pf + 1, PTS)][rl];
    float tmp = fd[min(pf + 2, PTS)][rl];  // in-flight prefetch
    float T3 = 1.0f, sw = 0.0f, rd = 0.0f;
    float f0 = 0.0f, f1 = 0.0f, f2 = 0.0f;
    #pragma unroll 2
    for (int it = 0; it < PTS; it++) {
        float pend = tmp;                              // completed ~1 iter ago
        float dfv = (pf < PTS) ? cur : 3.0e38f;
        bool tc = (pc < PTS) && (dc <= dfv);           // ties -> coarse (stable)
        float d = tc ? dc : dfv;
        pc += tc ? 1 : 0;
        dc = fmaf((float)pc, STEPV, NEARV);
        cur = tc ? cur : nxt;
        nxt = tc ? nxt : pend;                         // pend == fd[pf_old+2]
        pf += tc ? 0 : 1;
        tmp = fd[min(pf + 2, PTS)][rl];                // issue for next iter
        float e0 = __builtin_amdgcn_exp2f(fmaf(d, sA0, bA0));
        float e1 = __builtin_amdgcn_exp2f(fmaf(d, sA1, bA1));
        float e2 = __builtin_amdgcn_exp2f(fmaf(d, sA2, bA2));
        float e3 = __builtin_amdgcn_exp2f(fmaf(d, sA3, bA3));
        float e0c = fminf(e0, ECLAMP);
        float r0 = __builtin_amdgcn_rcpf(1.0f + e0c);  // op
        float m0 = e0c * r0;                           // 1-op, off-chain
        float v0 = __builtin_amdgcn_rcpf(1.0f + e1);
        float v1 = __builtin_amdgcn_rcpf(1.0f + e2);
        float v2 = __builtin_amdgcn_rcpf(1.0f + e3);
        float w = r0 * T3;
        f0 = fmaf(w, v0, f0);
        f1 = fmaf(w, v1, f1);
        f2 = fmaf(w, v2, f2);
        sw += w;
        rd  = fmaf(w, d, rd);
        T3 *= m0;                                      // chain: one v_mul
    }
    // pair fixup (linear in T3-start); symmetric -> both lanes same value
    float q3 = __shfl_xor(T3, 1, 64);
    float qs = __shfl_xor(sw, 1, 64);
    float q0 = __shfl_xor(f0, 1, 64);
    float q1 = __shfl_xor(f1, 1, 64);
    float q2 = __shfl_xor(f2, 1, 64);
    float qr = __shfl_xor(rd, 1, 64);
    float TA  = h ? q3 : T3;
    float swF = (h ? qs : sw) + TA * (h ? sw : qs);
    float f0F = (h ? q0 : f0) + TA * (h ? f0 : q0);
    float f1F = (h ? q1 : f1) + TA * (h ? f1 : q1);
    float f2F = (h ? q2 : f2) + TA * (h ? f2 : q2);
    float rdF = (h ? qr : rd) + TA * (h ? rd : qr);
    float fop  = fminf(fmaxf(swF, 0.0f), 1.0f);
    float rdep = rdF + (1.0f - fop) * 2.0f;            // d_all.max() == 2.0 exactly
    if (h == 0) {
        out[393216 + (b*3+0)*65536 + n] = f0F;
        out[393216 + (b*3+1)*65536 + n] = f1F;
        out[393216 + (b*3+2)*65536 + n] = f2F;
        out[786432 + r] = rdep;
    }

    // block min/max: wave shuffle reduce + cross-wave LDS combine
    unsigned ub  = __float_as_uint(rdep);              // rdep>0: u32 order == float order
    unsigned kmn = ub;                                 // pair-duplicates harmless
    unsigned kmx = ~ub;
    #pragma unroll
    for (int m = 32; m >= 1; m >>= 1) {
        unsigned omn = (unsigned)__shfl_xor((int)kmn, m, 64);
        unsigned omx = (unsigned)__shfl_xor((int)kmx, m, 64);
        kmn = (omn < kmn) ? omn : kmn;
        kmx = (omx < kmx) ? omx : kmx;
    }
    if ((tid & 63) == 0) { smn2[tid >> 6] = kmn; smx2[tid >> 6] = kmx; }
    __syncthreads();
    if (tid == 0) {
        bmm[2*blockIdx.x + 0] = min(smn2[0], smn2[1]); // plain stores: no init,
        bmm[2*blockIdx.x + 1] = min(smx2[0], smx2[1]); // no atomics, replay-safe
    }
}

__global__ __launch_bounds__(256) void nerf_norm(float* __restrict__ out,
                                                 const unsigned int* __restrict__ bmm)
{
    const int tid = threadIdx.x;
    // reduce 2048 per-block pairs (16KB, L2-resident broadcast)
    unsigned kmn = 0xFFFFFFFFu, kmx = 0xFFFFFFFFu;
    const uint2* bm2 = (const uint2*)bmm;
    #pragma unroll
    for (int t = 0; t < 8; t++) {
        uint2 p = bm2[tid + 256*t];
        kmn = min(kmn, p.x);
        kmx = min(kmx, p.y);
    }
    #pragma unroll
    for (int m = 32; m >= 1; m >>= 1) {
        unsigned omn = (unsigned)__shfl_xor((int)kmn, m, 64);
        unsigned omx = (unsigned)__shfl_xor((int)kmx, m, 64);
        kmn = (omn < kmn) ? omn : kmn;
        kmx = (omx < kmx) ? omx : kmx;
    }
    __shared__ unsigned smn[4], smx[4];
    if ((tid & 63) == 0) { smn[tid >> 6] = kmn; smx[tid >> 6] = kmx; }
    __syncthreads();
    kmn = min(min(smn[0], smn[1]), min(smn[2], smn[3]));
    kmx = min(min(smx[0], smx[1]), min(smx[2], smx[3]));
    float mn = __uint_as_float(kmn);
    float mx = __uint_as_float(~kmx);
    int idx = blockIdx.x * 256 + tid;
    float v = out[786432 + idx];
    out[786432 + idx] = (v - mn) * __builtin_amdgcn_rcpf(mx - mn);
}

extern "C" void kernel_launch(void* const* d_in, const int* in_sizes, int n_in,
                              void* d_out, int out_size, void* d_ws, size_t ws_size,
                              hipStream_t stream) {
    (void)in_sizes; (void)n_in; (void)out_size; (void)ws_size;
    const float* tm = (const float*)d_in[0];
    const float* wq = (const float*)d_in[1];
    float* out = (float*)d_out;
    unsigned int* bmm = (unsigned int*)d_ws;           // 2048 pairs = 16KB
    nerf_main<<<NRAYS/64, NT, 0, stream>>>(tm, wq, out, bmm);
    nerf_norm<<<NRAYS/256, 256, 0, stream>>>(out, bmm);
}

// Round 11
// 100.660 us; speedup vs baseline: 1.0909x; 1.0909x over previous
//
#include <hip/hip_runtime.h>
#include <math.h>

// R16: R14b base (proven 52.6us) + pipe-agnostic diet. R15 (2-lane split)
// regressed: streams/SIMD pinned at 2, kernel issue-bound -> TLP useless,
// only instruction/trans-slot removal helps. Changes vs R14b:
//  - INF pad row: fd[64]=3e38 preset, ph2 dump-writes -> new row 65; ph3's
//    exhaustion guards collapse to tc = (dc <= cur): -3 VALU/iter. Proofs:
//    emits == 64 exactly (c_hi <= ~1.0 < 65/64 forces pure-advance after
//    u>1), fine depths <= 2.0 < dc(pc=64)=2.0301 -> no bogus coarse takes.
//  - paired rcp for (e1,e2) in ph3: rcp(q1*q2) then 2 muls: -1 trans +5
//    VALU/iter (neutral if VALU-bound, ~12% of ph3 if trans-bound). e1,e2
//    clamped at 1e18 (product <= 1e36 no overflow; sigma saturates ~0).
//  - ph3 unroll 4; ph2 wslot update simplified (-1 op).
// Retained: off-chain mult-form chains, speculative opn, depth-2 ds prefetch,
// u-increment, per-block minmax stores (no memset). LDS fd[66][64]=16.9KB ->
// 8 blocks/CU = 2 waves/SIMD.

#define NT 64
#define PTS 64
#define NRAYS (2*256*256)
#define NEARV 0.1f
#define STEPV (1.9f/63.0f)
#define FAR63 (0.1f + 63.0f*(1.9f/63.0f))
#define NL2E (-1.4426950408889634f)
#define ECLAMP 1.0e37f
#define ECLAMP2 1.0e18f
#define BIGF 3.0e38f

__global__ __launch_bounds__(NT, 2) void nerf_main(
    const float* __restrict__ tm, const float* __restrict__ wq,
    float* __restrict__ out, unsigned int* __restrict__ bmm)
{
    __shared__ float fd[PTS + 2][NT];      // rows 0..63 fine depths, 64 = +INF
    const int tid = threadIdx.x;           // sentinel, 65 = junk dump row
    const int r = blockIdx.x * NT + tid;
    const int b = r >> 16, n = r & 65535;
    const int i = n >> 8, j = n & 255;

    float bA[4], sA[4];                    // feat[c]*(-log2e) = bA + d*sA
    {
        float cx = (1.0f + (float)j * (-2.0f/255.0f)) * (1.0f/4.2f);
        float cy = (1.0f + (float)i * (-2.0f/255.0f)) * (1.0f/4.2f);
        const float* tmb = tm + b*12;
        float dx = tmb[0]*cx + tmb[1]*cy + tmb[2];
        float dy = tmb[4]*cx + tmb[5]*cy + tmb[6];
        float dz = tmb[8]*cx + tmb[9]*cy + tmb[10];
        float ox = tmb[3], oy = tmb[7], oz = tmb[11];
        #pragma unroll
        for (int c = 0; c < 4; c++) {
            float s  = dx*wq[0*4+c] + dy*wq[1*4+c] + dz*wq[2*4+c];
            float bv = ox*wq[0*4+c] + oy*wq[1*4+c] + oz*wq[2*4+c]
                     + dx*wq[3*4+c] + dy*wq[4*4+c] + dz*wq[5*4+c];
            sA[c] = s * NL2E;
            bA[c] = bv * NL2E;
        }
    }

    // recurrence state: eV[c] = exp2(bA + d*sA) at the current coarse point,
    // kV[c] = per-step ratio exp2(sA*STEP). e00 = eV[0] at d = NEAR.
    float eV[4], kV[4], e00;
    #pragma unroll
    for (int c = 0; c < 4; c++) {
        eV[c] = __builtin_amdgcn_exp2f(bA[c] + NEARV*sA[c]);
        kV[c] = __builtin_amdgcn_exp2f(sA[c]*STEPV);
    }
    e00 = eV[0];

    // ---- phase 1: coarse march, zero exp2, 1-mul carried chain ----
    float T = 1.0f, S = 0.0f;
    float a0 = 0.0f, a1 = 0.0f, a2 = 0.0f;
    #pragma unroll 4
    for (int p = 0; p < PTS; p++) {
        float e0c = fminf(eV[0], ECLAMP);
        float r0 = __builtin_amdgcn_rcpf(1.0f + e0c);  // op
        float m0 = e0c * r0;                           // 1-op, off-chain
        float v0 = __builtin_amdgcn_rcpf(1.0f + eV[1]);
        float v1 = __builtin_amdgcn_rcpf(1.0f + eV[2]);
        float v2 = __builtin_amdgcn_rcpf(1.0f + eV[3]);
        eV[0] *= kV[0];
        eV[1] *= kV[1];
        eV[2] *= kV[2];
        eV[3] *= kV[3];
        float w = r0 * T;
        a0 = fmaf(w, v0, a0);
        a1 = fmaf(w, v1, a1);
        a2 = fmaf(w, v2, a2);
        S += w;
        T *= m0;                                       // chain: one v_mul
    }
    S += 64.0f * 1e-5f;                                // hoisted pad sum
    out[(b*3+0)*65536 + n] = a0;
    out[(b*3+1)*65536 + n] = a1;
    out[(b*3+2)*65536 + n] = a2;

    fd[PTS][tid] = BIGF;                               // +INF sentinel row

    // ---- phase 2: branchless sampling machine, zero exp2, speculative opn --
    float Sinv = __builtin_amdgcn_rcpf(S);
    float op0  = __builtin_amdgcn_rcpf(1.0f + e00);    // sigmoid at d = NEAR
    float T2   = 1.0f - op0;
    float c_lo = 0.0f;
    float c_hi = (op0 + 1e-5f) * Sinv;                 // cdf[0]
    int ind = 0, wslot = 0;
    float u = 0.015625f;                               // k/64, exact increments
    float bin_prev = NEARV;                            // bin_0 == NEAR always
    float eP  = e00 * kV[0];                           // index m = 1
    float opn = __builtin_amdgcn_rcpf(1.0f + eP);
    #pragma unroll 2
    for (int it = 0; it < 2*PTS; it++) {
        float eP2  = eP * kV[0];                       // speculative advance
        float opnB = __builtin_amdgcn_rcpf(1.0f + eP2);// off-chain rcp
        bool adv = (ind < PTS) && (c_hi <= u);         // searchsorted 'right'
        float wn  = opn * T2;
        float d0  = fmaf((float)(ind - 1), STEPV, NEARV);
        float den = c_hi - c_lo;
        den = (den < 1e-8f) ? 1.0f : den;              // ref guard
        float t = (u - c_lo) * __builtin_amdgcn_rcpf(den);
        t = fminf(fmaxf(t, 0.0f), 1.0f);
        float bin = fmaf(t, STEPV, d0);
        bin = (ind <= 0)   ? NEARV : bin;
        bin = (ind >= PTS) ? FAR63 : bin;
        float fdep = 0.5f * (bin_prev + bin);
        // emits are provably <=64 (wslot<64); defensive: overflow -> row 65
        int widx = adv ? (PTS + 1) : ((wslot < PTS) ? wslot : (PTS + 1));
        fd[widx][tid] = fdep;                          // unconditional ds_write
        float nc_hi = c_hi + (wn + 1e-5f) * Sinv;
        float nT2   = T2 * (1.0f - opn);
        bool advm   = adv && (ind < 62);               // m=min(ind+1,63) moves
        c_lo     = adv ? c_hi : c_lo;
        c_hi     = adv ? nc_hi : c_hi;
        T2       = adv ? nT2 : T2;
        bin_prev = adv ? bin_prev : bin;
        eP  = advm ? eP2  : eP;
        opn = advm ? opnB : opn;                       // select, not recompute
        ind += adv ? 1 : 0;
        u  += adv ? 0.0f : 0.015625f;                  // exact k/64 increments
        wslot += adv ? 0 : 1;                          // plain inc (guard in widx)
    }

    // ---- phase 3: merge, INF-sentinel (guard-free compare), paired rcp ----
    const float bA0 = bA[0], sA0 = sA[0], bA1 = bA[1], sA1 = sA[1];
    const float bA2 = bA[2], sA2 = sA[2], bA3 = bA[3], sA3 = sA[3];
    float T3 = 1.0f, sw = 0.0f, rd = 0.0f;
    float f0 = 0.0f, f1 = 0.0f, f2 = 0.0f;
    int pc = 0, pf = 0;
    float dc = NEARV;
    float cur = fd[0][tid], nxt = fd[1][tid];
    float tmp = fd[2][tid];                            // in-flight prefetch
    #pragma unroll 4
    for (int it = 0; it < 2*PTS; it++) {
        float pend = tmp;                              // completed ~1 iter ago
        bool tc = (dc <= cur);                         // ties -> coarse; INF
        float d = tc ? dc : cur;                       //   sentinel ends fine
        pc += tc ? 1 : 0;
        dc = fmaf((float)pc, STEPV, NEARV);
        cur = tc ? cur : nxt;
        nxt = tc ? nxt : pend;                         // pend == fd[pf_old+2]
        pf += tc ? 0 : 1;
        tmp = fd[min(pf + 2, PTS)][tid];               // issue for next iter
        float e0 = __builtin_amdgcn_exp2f(fmaf(d, sA0, bA0));
        float e1 = __builtin_amdgcn_exp2f(fmaf(d, sA1, bA1));
        float e2 = __builtin_amdgcn_exp2f(fmaf(d, sA2, bA2));
        float e3 = __builtin_amdgcn_exp2f(fmaf(d, sA3, bA3));
        float e0c = fminf(e0, ECLAMP);
        float r0 = __builtin_amdgcn_rcpf(1.0f + e0c);  // op
        float m0 = e0c * r0;                           // 1-op, off-chain
        float e1c = fminf(e1, ECLAMP2);                // clamp so q1*q2 finite
        float e2c = fminf(e2, ECLAMP2);
        float q1 = 1.0f + e1c, q2 = 1.0f + e2c;
        float r12 = __builtin_amdgcn_rcpf(q1 * q2);    // one rcp, two sigmoids
        float v0 = r12 * q2;
        float v1 = r12 * q1;
        float v2 = __builtin_amdgcn_rcpf(1.0f + e3);
        float w = r0 * T3;
        f0 = fmaf(w, v0, f0);
        f1 = fmaf(w, v1, f1);
        f2 = fmaf(w, v2, f2);
        sw += w;
        rd  = fmaf(w, d, rd);
        T3 *= m0;                                      // chain: one v_mul
    }

    out[393216 + (b*3+0)*65536 + n] = f0;
    out[393216 + (b*3+1)*65536 + n] = f1;
    out[393216 + (b*3+2)*65536 + n] = f2;
    float fop  = fminf(fmaxf(sw, 0.0f), 1.0f);
    float rdep = rd + (1.0f - fop) * 2.0f;             // d_all.max() == 2.0 exactly
    out[786432 + r] = rdep;

    unsigned ub  = __float_as_uint(rdep);              // rdep>0: u32 order == float order
    unsigned kmn = ub;
    unsigned kmx = ~ub;
    #pragma unroll
    for (int m = 32; m >= 1; m >>= 1) {
        unsigned omn = (unsigned)__shfl_xor((int)kmn, m, 64);
        unsigned omx = (unsigned)__shfl_xor((int)kmx, m, 64);
        kmn = (omn < kmn) ? omn : kmn;
        kmx = (omx < kmx) ? omx : kmx;
    }
    if (tid == 0) {
        bmm[2*blockIdx.x + 0] = kmn;                   // plain stores: no init,
        bmm[2*blockIdx.x + 1] = kmx;                   // no atomics, replay-safe
    }
}

__global__ __launch_bounds__(256) void nerf_norm(float* __restrict__ out,
                                                 const unsigned int* __restrict__ bmm)
{
    const int tid = threadIdx.x;
    // reduce 2048 per-block pairs (16KB, L2-resident broadcast)
    unsigned kmn = 0xFFFFFFFFu, kmx = 0xFFFFFFFFu;
    const uint2* bm2 = (const uint2*)bmm;
    #pragma unroll
    for (int t = 0; t < 8; t++) {
        uint2 p = bm2[tid + 256*t];
        kmn = min(kmn, p.x);
        kmx = min(kmx, p.y);
    }
    #pragma unroll
    for (int m = 32; m >= 1; m >>= 1) {
        unsigned omn = (unsigned)__shfl_xor((int)kmn, m, 64);
        unsigned omx = (unsigned)__shfl_xor((int)kmx, m, 64);
        kmn = (omn < kmn) ? omn : kmn;
        kmx = (omx < kmx) ? omx : kmx;
    }
    __shared__ unsigned smn[4], smx[4];
    if ((tid & 63) == 0) { smn[tid >> 6] = kmn; smx[tid >> 6] = kmx; }
    __syncthreads();
    kmn = min(min(smn[0], smn[1]), min(smn[2], smn[3]));
    kmx = min(min(smx[0], smx[1]), min(smx[2], smx[3]));
    float mn = __uint_as_float(kmn);
    float mx = __uint_as_float(~kmx);
    int idx = blockIdx.x * 256 + tid;
    float v = out[786432 + idx];
    out[786432 + idx] = (v - mn) * __builtin_amdgcn_rcpf(mx - mn);
}

extern "C" void kernel_launch(void* const* d_in, const int* in_sizes, int n_in,
                              void* d_out, int out_size, void* d_ws, size_t ws_size,
                              hipStream_t stream) {
    (void)in_sizes; (void)n_in; (void)out_size; (void)ws_size;
    const float* tm = (const float*)d_in[0];
    const float* wq = (const float*)d_in[1];
    float* out = (float*)d_out;
    unsigned int* bmm = (unsigned int*)d_ws;           // 2048 pairs = 16KB
    nerf_main<<<NRAYS/NT, NT, 0, stream>>>(tm, wq, out, bmm);
    nerf_norm<<<NRAYS/256, 256, 0, stream>>>(out, bmm);
}